// Round 9
// baseline (169.801 us; speedup 1.0000x reference)
//
#include <hip/hip_runtime.h>
#include <stdint.h>

// MultiHeadSelfAttention: E=1024, H=16, S=4096, half=512, Dh=32, scale=sqrt(64)=8
// R18: non-attn pipeline restructured.
//  - Single fused QKV GEMM: B = [Wq|Wk|Wv] (contiguous, 1536x512, SC_Q folded
//    into Wq at convert) -> QKV[4096][1536]. 64x128 tiles, 768 blocks (3/CU).
//  - combine_kernel DELETED: outproj's A-staging computes (Op0+Op1)/(l0+l1)
//    inline (reg-staged A, DMA B). 64x128 tiles, 512 blocks (2/CU).
//  - attn unchanged from R17 (59us proven: 8 waves, KVBLK=128, P-in-registers,
//    XCD panel swizzle, ns=2) except QKV ld=1536 pointers.
// GEMM staging: global_load_lds width-16 DMA, lane-linear LDS [rows][32] u16,
// XOR chunk swizzle (chunk ^= row&3) on BOTH source addr and ds_read addr.

#define SEQ    4096
#define DMODEL 1024
#define DHALF  512
#define NH     16
#define DH     32
#define LDQ    1536   // QKV row stride in u16

typedef __attribute__((ext_vector_type(4))) float facc4;
typedef __attribute__((ext_vector_type(8))) short bfrag8;

#define MFMA_BF16(a, b, c) __builtin_amdgcn_mfma_f32_16x16x32_bf16((a), (b), (c), 0, 0, 0)

// global -> LDS direct DMA, 16B per lane; LDS dest = base + lane*16 (HW).
static __device__ __forceinline__ void gll16(const void* g, void* l) {
    typedef const __attribute__((address_space(1))) void GV;
    typedef __attribute__((address_space(3))) void LV;
    __builtin_amdgcn_global_load_lds((GV*)g, (LV*)l, 16, 0, 0);
}

static __device__ __forceinline__ uint16_t f2b(float x) {
    uint32_t u = __float_as_uint(x);
    return (uint16_t)((u + 0x7FFFu + ((u >> 16) & 1u)) >> 16);  // RNE
}
static __device__ __forceinline__ float b2f(uint16_t b) {
    return __uint_as_float(((uint32_t)b) << 16);
}

// 8x fp32 -> 8x bf16 (round-half-away; ties measure-small) via 2add+1perm pairs
static __device__ __forceinline__ bfrag8 cvt8perm(float4 a, float4 b) {
    uint32_t u0 = __float_as_uint(a.x) + 0x8000u, u1 = __float_as_uint(a.y) + 0x8000u;
    uint32_t u2 = __float_as_uint(a.z) + 0x8000u, u3 = __float_as_uint(a.w) + 0x8000u;
    uint32_t u4 = __float_as_uint(b.x) + 0x8000u, u5 = __float_as_uint(b.y) + 0x8000u;
    uint32_t u6 = __float_as_uint(b.z) + 0x8000u, u7 = __float_as_uint(b.w) + 0x8000u;
    union { uint32_t w[4]; bfrag8 r; } u;
    u.w[0] = __builtin_amdgcn_perm(u1, u0, 0x07060302u);
    u.w[1] = __builtin_amdgcn_perm(u3, u2, 0x07060302u);
    u.w[2] = __builtin_amdgcn_perm(u5, u4, 0x07060302u);
    u.w[3] = __builtin_amdgcn_perm(u7, u6, 0x07060302u);
    return u.r;
}

#define SC_Q (0.125f * 1.4426950408889634f)  // softmax scale * log2(e), folded into Wq

// Weights fp32->bf16. Blocks [0,128) Wq*SC_Q -> wqkv rows 0-511; [128,256) Wk
// -> rows 512-1023; [256,384) Wv -> rows 1024-1535; [384,640) Wo -> wo.
// Blocks [640,1664): x left-half fp32 -> xb bf16 (4096x512, row-major).
__global__ __launch_bounds__(256) void convert_w(
    const float* __restrict__ Wq, const float* __restrict__ Wk,
    const float* __restrict__ Wv, const float* __restrict__ Wo,
    const float* __restrict__ x,
    uint16_t* __restrict__ wqkv, uint16_t* __restrict__ wo,
    uint16_t* __restrict__ xb)
{
    int zz = blockIdx.x;
    if (zz >= 640) {
        size_t g = (size_t)(zz - 640) * 2048 + (size_t)threadIdx.x * 8;
        int row = (int)(g >> 9);
        int col = (int)(g & 511);
        const float* src = &x[(size_t)row * DMODEL + col];
        float4 a = *(const float4*)src;
        float4 b = *(const float4*)(src + 4);
        *(bfrag8*)&xb[g] = cvt8perm(a, b);
        return;
    }
    const float* src; uint16_t* dst; size_t off; float sc = 1.0f;
    if      (zz < 128) { src = Wq; dst = wqkv;          off = (size_t)zz * 2048; sc = SC_Q; }
    else if (zz < 256) { src = Wk; dst = wqkv + 262144; off = (size_t)(zz - 128) * 2048; }
    else if (zz < 384) { src = Wv; dst = wqkv + 524288; off = (size_t)(zz - 256) * 2048; }
    else               { src = Wo; dst = wo;            off = (size_t)(zz - 384) * 2048; }
    size_t i = off + (size_t)threadIdx.x * 8;
    float4 a = *(const float4*)&src[i];
    float4 b = *(const float4*)&src[i + 4];
    a.x *= sc; a.y *= sc; a.z *= sc; a.w *= sc;
    b.x *= sc; b.y *= sc; b.z *= sc; b.w *= sc;
    *(bfrag8*)&dst[i] = cvt8perm(a, b);
}

// ---------------------------------------------------------------------------
// Fused QKV GEMM: QKV[4096][1536] = xb[4096][512] x Wqkv[1536][512]^T.
// 64x128 tile, DMA staging, double-buffered. Grid (12, 64) = 768 blocks.
// Swapped-operand MFMA: lane (lo,quad) holds C[row=..+lo][col=..+quad*4+r].
// ---------------------------------------------------------------------------
__global__ __launch_bounds__(256) void qkv_kernel(
    const uint16_t* __restrict__ xb, const uint16_t* __restrict__ Wqkv,
    uint16_t* __restrict__ QKV)
{
    __shared__ __align__(16) uint16_t As[2][64 * 32];
    __shared__ __align__(16) uint16_t Bs[2][128 * 32];

    const int tid  = threadIdx.x;
    const int lane = tid & 63;
    const int wv   = tid >> 6;
    const int lo   = lane & 15;
    const int quad = lane >> 4;
    const int m0   = blockIdx.y * 64;
    const int n0   = blockIdx.x * 128;
    const int rt   = (wv >> 1) * 32;
    const int ct   = (wv & 1) * 64;

    const facc4 ZACC = {0.f, 0.f, 0.f, 0.f};
    facc4 acc[2][4];
#pragma unroll
    for (int i = 0; i < 2; ++i)
#pragma unroll
        for (int j = 0; j < 4; ++j) acc[i][j] = ZACC;

    const int lrow = lane >> 2;
    const int scol = (((lane & 3) ^ (lrow & 3)) << 3);  // swizzled source k-col
    const uint16_t* gA  = &xb[(size_t)(m0 + wv * 16 + lrow) * DHALF + scol];
    const uint16_t* gB0 = &Wqkv[(size_t)(n0 + wv * 32 + lrow) * DHALF + scol];
    const uint16_t* gB1 = gB0 + (size_t)16 * DHALF;
    const int dA  = wv * 512;
    const int dB0 = wv * 1024, dB1 = dB0 + 512;
    const int rdo = lo * 32 + ((quad ^ (lo & 3)) << 3);

    gll16(gA, &As[0][dA]);
    gll16(gB0, &Bs[0][dB0]); gll16(gB1, &Bs[0][dB1]);
    __syncthreads();

    int p = 0;
    for (int kt = 0; kt < DHALF; kt += 32) {
        const bool more = (kt + 32 < DHALF);
        if (more) {
            gll16(gA + kt + 32, &As[1 - p][dA]);
            gll16(gB0 + kt + 32, &Bs[1 - p][dB0]);
            gll16(gB1 + kt + 32, &Bs[1 - p][dB1]);
        }

        bfrag8 af[2], bf[4];
#pragma unroll
        for (int i = 0; i < 2; ++i)
            af[i] = *(const bfrag8*)&As[p][rt * 32 + i * 512 + rdo];
#pragma unroll
        for (int j = 0; j < 4; ++j)
            bf[j] = *(const bfrag8*)&Bs[p][ct * 32 + j * 512 + rdo];
#pragma unroll
        for (int i = 0; i < 2; ++i)
#pragma unroll
            for (int j = 0; j < 4; ++j)
                acc[i][j] = MFMA_BF16(bf[j], af[i], acc[i][j]);  // swapped

        if (more) {
            __syncthreads();
            p ^= 1;
        }
    }

#pragma unroll
    for (int i = 0; i < 2; ++i) {
        const size_t row = (size_t)(m0 + rt + i * 16 + lo);
#pragma unroll
        for (int j = 0; j < 4; ++j) {
            const int colb = n0 + ct + j * 16 + quad * 4;
            uint2 o;
            o.x = (uint32_t)f2b(acc[i][j][0]) | ((uint32_t)f2b(acc[i][j][1]) << 16);
            o.y = (uint32_t)f2b(acc[i][j][2]) | ((uint32_t)f2b(acc[i][j][3]) << 16);
            *(uint2*)&QKV[row * LDQ + colb] = o;
        }
    }
}

// ---------------------------------------------------------------------------
// outproj with fused split-K combine: A row r, k-col c is
// (Op0[r][c]+Op1[r][c]) / (l0[h][r]+l1[h][r]), h = c>>5, computed during
// reg-staging (same XOR-chunk LDS layout as the DMA path). B = Wob via DMA.
// C = Y f32 [4096][1024] + bias. Grid (8, 64) = 512 blocks.
// ---------------------------------------------------------------------------
__global__ __launch_bounds__(256) void outproj_kernel(
    const uint16_t* __restrict__ Op, const float* __restrict__ lbuf,
    const uint16_t* __restrict__ Wob, const float* __restrict__ bo,
    float* __restrict__ Y)
{
    __shared__ __align__(16) uint16_t As[2][64 * 32];
    __shared__ __align__(16) uint16_t Bs[2][128 * 32];

    const int tid  = threadIdx.x;
    const int lane = tid & 63;
    const int wv   = tid >> 6;
    const int lo   = lane & 15;
    const int quad = lane >> 4;
    const int m0   = blockIdx.y * 64;
    const int n0   = blockIdx.x * 128;
    const int rt   = (wv >> 1) * 32;
    const int ct   = (wv & 1) * 64;

    const facc4 ZACC = {0.f, 0.f, 0.f, 0.f};
    facc4 acc[2][4];
#pragma unroll
    for (int i = 0; i < 2; ++i)
#pragma unroll
        for (int j = 0; j < 4; ++j) acc[i][j] = ZACC;

    const int lrow = lane >> 2;
    const int scol = (((lane & 3) ^ (lrow & 3)) << 3);
    const int arow = m0 + wv * 16 + lrow;
    const uint16_t* gO0 = &Op[(size_t)arow * DHALF + scol];
    const uint16_t* gO1 = gO0 + (size_t)SEQ * DHALF;
    const float* lb0 = &lbuf[arow];
    const float* lb1 = &lbuf[(size_t)NH * SEQ + arow];
    const uint16_t* gB0 = &Wob[(size_t)(n0 + wv * 32 + lrow) * DHALF + scol];
    const uint16_t* gB1 = gB0 + (size_t)16 * DHALF;
    const int dA  = wv * 512 + lane * 8;   // this thread's A ds_write slot (u16)
    const int dB0 = wv * 1024, dB1 = dB0 + 512;
    const int rdo = lo * 32 + ((quad ^ (lo & 3)) << 3);

#define PACKA(A0, A1, INV)                                                    \
    ({ float4 fa_, fb_;                                                       \
       fa_.x = (b2f((uint16_t)(A0)[0]) + b2f((uint16_t)(A1)[0])) * (INV);     \
       fa_.y = (b2f((uint16_t)(A0)[1]) + b2f((uint16_t)(A1)[1])) * (INV);     \
       fa_.z = (b2f((uint16_t)(A0)[2]) + b2f((uint16_t)(A1)[2])) * (INV);     \
       fa_.w = (b2f((uint16_t)(A0)[3]) + b2f((uint16_t)(A1)[3])) * (INV);     \
       fb_.x = (b2f((uint16_t)(A0)[4]) + b2f((uint16_t)(A1)[4])) * (INV);     \
       fb_.y = (b2f((uint16_t)(A0)[5]) + b2f((uint16_t)(A1)[5])) * (INV);     \
       fb_.z = (b2f((uint16_t)(A0)[6]) + b2f((uint16_t)(A1)[6])) * (INV);     \
       fb_.w = (b2f((uint16_t)(A0)[7]) + b2f((uint16_t)(A1)[7])) * (INV);     \
       cvt8perm(fa_, fb_); })

    {   // prologue: k-slab 0 (head 0)
        bfrag8 a0 = *(const bfrag8*)gO0;
        bfrag8 a1 = *(const bfrag8*)gO1;
        float inv = 1.0f / (lb0[0] + lb1[0]);
        *(bfrag8*)&As[0][dA] = PACKA(a0, a1, inv);
        gll16(gB0, &Bs[0][dB0]); gll16(gB1, &Bs[0][dB1]);
    }
    __syncthreads();

    int p = 0;
    for (int kt = 0; kt < DHALF; kt += 32) {
        const bool more = (kt + 32 < DHALF);
        bfrag8 na0, na1; float nl = 1.0f;
        if (more) {  // issue next A loads early; B DMA fire-and-forget
            na0 = *(const bfrag8*)(gO0 + kt + 32);
            na1 = *(const bfrag8*)(gO1 + kt + 32);
            const int hh = (kt + 32) >> 5;
            nl = lb0[(size_t)hh * SEQ] + lb1[(size_t)hh * SEQ];
            gll16(gB0 + kt + 32, &Bs[1 - p][dB0]);
            gll16(gB1 + kt + 32, &Bs[1 - p][dB1]);
        }

        bfrag8 af[2], bf[4];
#pragma unroll
        for (int i = 0; i < 2; ++i)
            af[i] = *(const bfrag8*)&As[p][rt * 32 + i * 512 + rdo];
#pragma unroll
        for (int j = 0; j < 4; ++j)
            bf[j] = *(const bfrag8*)&Bs[p][ct * 32 + j * 512 + rdo];
#pragma unroll
        for (int i = 0; i < 2; ++i)
#pragma unroll
            for (int j = 0; j < 4; ++j)
                acc[i][j] = MFMA_BF16(bf[j], af[i], acc[i][j]);  // swapped

        if (more) {
            float inv = 1.0f / nl;
            *(bfrag8*)&As[1 - p][dA] = PACKA(na0, na1, inv);
            __syncthreads();
            p ^= 1;
        }
    }
#undef PACKA

#pragma unroll
    for (int i = 0; i < 2; ++i) {
        const size_t row = (size_t)(m0 + rt + i * 16 + lo);
#pragma unroll
        for (int j = 0; j < 4; ++j) {
            const int colb = n0 + ct + j * 16 + quad * 4;
            float4 bv = *(const float4*)&bo[colb];
            float4 o;
            o.x = acc[i][j][0] + bv.x;
            o.y = acc[i][j][1] + bv.y;
            o.z = acc[i][j][2] + bv.z;
            o.w = acc[i][j][3] + bv.w;
            *(float4*)&Y[row * DMODEL + colb] = o;
        }
    }
}

// ---------------------------------------------------------------------------
// Split-K flash attention (R17 structure, ns=2), reading the fused QKV buffer
// (ld=1536: Q cols 0-511, K 512-1023, V 1024-1535). 512 threads / 8 waves;
// wave owns 32 q-rows (q-block 256); KVBLK=128 as two 64-key halves. P in
// registers: swapped QK^T mfma(K,Q) gives lane (lo,quad) P[q=lo] at keys
// 16t+4quad+r; V staged key-permuted so PV's B-slot order matches P's register
// order. 2-buffer Ks/Vt, 1 barrier/tile. XCD panel swizzle.
// ---------------------------------------------------------------------------
__global__ __launch_bounds__(512) void attn_kernel(
    const uint16_t* __restrict__ QKV, uint16_t* __restrict__ Op,
    float* __restrict__ lbuf, int kspan)
{
    __shared__ __align__(16) uint16_t Ks[2][128 * 40];  // K tile [key][d]
    __shared__ __align__(16) uint16_t Vt[2][32 * 128];  // V^T [d][perm(key)], swizzled

    const int tid  = threadIdx.x;
    const int lane = tid & 63;
    const int wv   = tid >> 6;          // 0..7
    const int lo   = lane & 15;
    const int quad = lane >> 4;

    // XCD panel swizzle: grid (16,16,ns); f = bx + 16*by + 256*bz.
    // pp = (f&7)|((f>>7)<<3); j = (f>>3)&15. Bijective for ns in {2,4}; all 16
    // blocks of panel pp share f mod 8 (= one XCD under round-robin dispatch).
    const int f  = blockIdx.x + 16 * blockIdx.y + 256 * blockIdx.z;
    const int pp = (f & 7) | ((f >> 7) << 3);
    const int h  = pp & 15;
    const int sp = pp >> 4;
    const int q0 = ((f >> 3) & 15) * 256;

    const int srow = tid >> 2;          // 0..127: staged K/V key row
    const int skq  = (tid & 3) * 8;

    const facc4 ZACC = {0.f, 0.f, 0.f, 0.f};

    bfrag8 qf[2];
    qf[0] = *(const bfrag8*)&QKV[(size_t)(q0 + wv * 32 + lo) * LDQ + h * DH + quad * 8];
    qf[1] = *(const bfrag8*)&QKV[(size_t)(q0 + wv * 32 + 16 + lo) * LDQ + h * DH + quad * 8];

    bfrag8 ones;
#pragma unroll
    for (int j = 0; j < 8; ++j) ones[j] = (short)0x3F80;  // bf16 1.0

    // V staging scatter: key srow -> permuted column p(srow); per-d Rd rotation
    // (mod-16 on column groups, bank effect is mod-8) spreads banks.
    int vt_w[8];
    {
        int pb = ((srow >> 5) << 2) | ((srow >> 2) & 3);   // p >> 3, 0..15
        int pw = (((srow >> 4) & 1) << 2) | (srow & 3);    // p & 7
#pragma unroll
        for (int j = 0; j < 8; ++j) {
            int d  = skq + j;
            int Rd = ((d & 7) + 2 * (d >> 3)) & 7;
            vt_w[j] = d * 128 + (((pb + Rd) & 15) << 3) + pw;
        }
    }
    int vt_r[4][2];
#pragma unroll
    for (int dt = 0; dt < 2; ++dt) {
        int d  = dt * 16 + lo;
        int Rd = ((d & 7) + 2 * (d >> 3)) & 7;
#pragma unroll
        for (int c = 0; c < 4; ++c)
            vt_r[c][dt] = d * 128 + ((((c * 4 + quad) + Rd) & 15) << 3);
    }
    const int ks_r = lo * 40 + quad * 8;

    const uint16_t* kp = &QKV[(size_t)(sp * kspan + srow) * LDQ + DHALF + h * DH + skq];
    const uint16_t* vp = &QKV[(size_t)(sp * kspan + srow) * LDQ + 2 * DHALF + h * DH + skq];

    facc4 oacc[2][2], oaccL[2];
    oacc[0][0] = ZACC; oacc[0][1] = ZACC;
    oacc[1][0] = ZACC; oacc[1][1] = ZACC;
    oaccL[0] = ZACC; oaccL[1] = ZACC;

    float4 kreg = *(const float4*)kp;
    float4 vreg = *(const float4*)vp;
    kp += (size_t)128 * LDQ;
    vp += (size_t)128 * LDQ;

#define STAGE(BUF) do {                                                       \
        *(float4*)&Ks[BUF][srow * 40 + skq] = kreg;                           \
        const uint16_t* vsp = (const uint16_t*)&vreg;                         \
        _Pragma("unroll")                                                     \
        for (int j = 0; j < 8; ++j) Vt[BUF][vt_w[j]] = vsp[j];                \
    } while (0)

// One 64-key half (HH in {0,1}) of a 128-key tile: QK^T + exp + pack + PV.
#define HALF(BUF, HH) do {                                                    \
        uint2 w0[4], w1[4];                                                   \
        _Pragma("unroll")                                                     \
        for (int t4 = 0; t4 < 4; ++t4) {                                      \
            bfrag8 kf = *(const bfrag8*)&Ks[BUF][(4 * HH + t4) * 640 + ks_r]; \
            facc4 s0 = MFMA_BF16(kf, qf[0], ZACC);                            \
            facc4 s1 = MFMA_BF16(kf, qf[1], ZACC);                            \
            uint32_t a0 = __float_as_uint(__builtin_amdgcn_exp2f(s0[0])) + 0x8000u; \
            uint32_t a1 = __float_as_uint(__builtin_amdgcn_exp2f(s0[1])) + 0x8000u; \
            uint32_t a2 = __float_as_uint(__builtin_amdgcn_exp2f(s0[2])) + 0x8000u; \
            uint32_t a3 = __float_as_uint(__builtin_amdgcn_exp2f(s0[3])) + 0x8000u; \
            w0[t4].x = __builtin_amdgcn_perm(a1, a0, 0x07060302u);            \
            w0[t4].y = __builtin_amdgcn_perm(a3, a2, 0x07060302u);            \
            uint32_t b0 = __float_as_uint(__builtin_amdgcn_exp2f(s1[0])) + 0x8000u; \
            uint32_t b1 = __float_as_uint(__builtin_amdgcn_exp2f(s1[1])) + 0x8000u; \
            uint32_t b2 = __float_as_uint(__builtin_amdgcn_exp2f(s1[2])) + 0x8000u; \
            uint32_t b3 = __float_as_uint(__builtin_amdgcn_exp2f(s1[3])) + 0x8000u; \
            w1[t4].x = __builtin_amdgcn_perm(b1, b0, 0x07060302u);            \
            w1[t4].y = __builtin_amdgcn_perm(b3, b2, 0x07060302u);            \
        }                                                                     \
        union PU { uint2 u2[2]; bfrag8 f; } pu;                               \
        bfrag8 pf0[2], pf1[2];                                                \
        pu.u2[0] = w0[0]; pu.u2[1] = w0[1]; pf0[0] = pu.f;                    \
        pu.u2[0] = w0[2]; pu.u2[1] = w0[3]; pf0[1] = pu.f;                    \
        pu.u2[0] = w1[0]; pu.u2[1] = w1[1]; pf1[0] = pu.f;                    \
        pu.u2[0] = w1[2]; pu.u2[1] = w1[3]; pf1[1] = pu.f;                    \
        _Pragma("unroll")                                                     \
        for (int cc = 0; cc < 2; ++cc) {                                      \
            _Pragma("unroll")                                                 \
            for (int dt = 0; dt < 2; ++dt) {                                  \
                bfrag8 vf = *(const bfrag8*)&Vt[BUF][vt_r[2 * HH + cc][dt]];  \
                oacc[0][dt] = MFMA_BF16(pf0[cc], vf, oacc[0][dt]);            \
                oacc[1][dt] = MFMA_BF16(pf1[cc], vf, oacc[1][dt]);            \
            }                                                                 \
            oaccL[0] = MFMA_BF16(pf0[cc], ones, oaccL[0]);                    \
            oaccL[1] = MFMA_BF16(pf1[cc], ones, oaccL[1]);                    \
        }                                                                     \
    } while (0)

#define TILE(BUF) do { HALF(BUF, 0); HALF(BUF, 1); } while (0)

    // prologue: tile 0 into buffer 0
    STAGE(0);
    __syncthreads();

    const int nt = kspan >> 7;  // 16 at ns=2; always even
    for (int t = 0; t < nt; t += 2) {
        // tile t from buf0; prefetch t+1 (always exists: nt even)
        kreg = *(const float4*)kp;
        vreg = *(const float4*)vp;
        kp += (size_t)128 * LDQ; vp += (size_t)128 * LDQ;
        TILE(0);
        STAGE(1);
        __syncthreads();

        // tile t+1 from buf1; prefetch/restage t+2 if it exists
        const bool more = (t + 2 < nt);
        if (more) {
            kreg = *(const float4*)kp;
            vreg = *(const float4*)vp;
            kp += (size_t)128 * LDQ; vp += (size_t)128 * LDQ;
        }
        TILE(1);
        if (more) {
            STAGE(0);
            __syncthreads();
        }
    }
#undef STAGE
#undef HALF
#undef TILE

    // l for q-row (g*16 + quad*4 + r) sits in oaccL[g][r] (same on all lo lanes)
    if (lo == 0) {
#pragma unroll
        for (int g = 0; g < 2; ++g)
#pragma unroll
            for (int r = 0; r < 4; ++r)
                lbuf[((size_t)sp * NH + h) * SEQ + q0 + wv * 32 + g * 16 + quad * 4 + r] =
                    oaccL[g][r];
    }

    uint16_t* Od = Op + (size_t)sp * SEQ * DHALF;
#pragma unroll
    for (int g = 0; g < 2; ++g) {
#pragma unroll
        for (int r = 0; r < 4; ++r) {
            int row = q0 + wv * 32 + g * 16 + quad * 4 + r;
            Od[(size_t)row * DHALF + h * DH + lo]      = f2b(oacc[g][0][r]);  // unnormalized
            Od[(size_t)row * DHALF + h * DH + 16 + lo] = f2b(oacc[g][1][r]);
        }
    }
}

extern "C" void kernel_launch(void* const* d_in, const int* in_sizes, int n_in,
                              void* d_out, int out_size, void* d_ws, size_t ws_size,
                              hipStream_t stream)
{
    const float* x  = (const float*)d_in[0];
    const float* Wq = (const float*)d_in[1];
    const float* Wk = (const float*)d_in[2];
    const float* Wv = (const float*)d_in[3];
    const float* Wo = (const float*)d_in[4];
    const float* bo = (const float*)d_in[5];

    // ws (u16 elems): Wqkv 786432 | Wob 524288 | QKV 6291456 | Op 2x2097152
    // | lbuf 2*16*4096 f32. Total ~24.1 MB. xb aliases Op (live convert->qkv;
    // attn overwrites Op only after qkv completes -- stream-ordered).
    uint16_t* Wqkv = (uint16_t*)d_ws;
    uint16_t* Wob  = Wqkv + 786432;
    uint16_t* QKV  = Wob + 524288;
    uint16_t* Op   = QKV + (size_t)SEQ * LDQ;
    float*  lbuf   = (float*)(Op + (size_t)2 * SEQ * DHALF);
    uint16_t* xb   = Op;  // alias

    convert_w<<<1664, 256, 0, stream>>>(Wq, Wk, Wv, Wo, x, Wqkv, Wob, xb);
    qkv_kernel<<<dim3(LDQ / 128, SEQ / 64), 256, 0, stream>>>(xb, Wqkv, QKV);
    attn_kernel<<<dim3(SEQ / 256, NH, 2), 512, 0, stream>>>(QKV, Op, lbuf, SEQ / 2);
    outproj_kernel<<<dim3(DMODEL / 128, SEQ / 64), 256, 0, stream>>>(
        Op, lbuf, Wob, bo, (float*)d_out);
}